// Round 7
// baseline (575.547 us; speedup 1.0000x reference)
//
#include <hip/hip_runtime.h>

#define BDIM 16
#define HSZ 64
#define NHEAD 16
#define LOG2E 1.4426950408889634f

typedef __bf16 bf16x8 __attribute__((ext_vector_type(8)));
typedef float f32x4 __attribute__((ext_vector_type(4)));
typedef float f32x2 __attribute__((ext_vector_type(2)));
typedef unsigned short us8 __attribute__((ext_vector_type(8)));
typedef unsigned int u32;

__device__ __forceinline__ unsigned short f2bf(float f) {
    u32 u = __float_as_uint(f);
    return (unsigned short)((u + 0x7fffu + ((u >> 16) & 1u)) >> 16);
}

__device__ __forceinline__ void gload_lds16(const void* g, void* l) {
    __builtin_amdgcn_global_load_lds(
        (const __attribute__((address_space(1))) void*)g,
        (__attribute__((address_space(3))) void*)l, 16, 0, 0);
}

// ---- two-level grid barrier (R6 post-mortem: single-line spin with 768
// pollers cost ~100us/barrier; this splits arrival into 8 groups on
// separate 128B lines, one global RMW per group, and read-only flag
// polling spread over 8 lines). Layout per set (u32 idx): lbar[g]=g*32,
// gbar=256, lflag[g]=288+g*32. Sets are 1024 u32 apart; memset per iter.
#define PERGRP 128   // 1024 blocks / 8 groups
__device__ __forceinline__ void gsync2(unsigned* base, int grp) {
    __syncthreads();
    if (threadIdx.x == 0) {
        unsigned old = __hip_atomic_fetch_add(base + grp * 32, 1u,
                         __ATOMIC_ACQ_REL, __HIP_MEMORY_SCOPE_AGENT);
        if (old == PERGRP - 1) {            // last arriver of this group
            unsigned g = __hip_atomic_fetch_add(base + 256, 1u,
                           __ATOMIC_ACQ_REL, __HIP_MEMORY_SCOPE_AGENT);
            if (g == 7) {                   // globally last: release all
#pragma unroll
                for (int i = 0; i < 8; ++i)
                    __hip_atomic_store(base + 288 + i * 32, 1u,
                                       __ATOMIC_RELEASE, __HIP_MEMORY_SCOPE_AGENT);
            } else {
                while (__hip_atomic_load(base + 288 + grp * 32,
                         __ATOMIC_ACQUIRE, __HIP_MEMORY_SCOPE_AGENT) == 0)
                    __builtin_amdgcn_s_sleep(8);
            }
        } else {
            while (__hip_atomic_load(base + 288 + grp * 32,
                     __ATOMIC_ACQUIRE, __HIP_MEMORY_SCOPE_AGENT) == 0)
                __builtin_amdgcn_s_sleep(8);
        }
    }
    __syncthreads();
}

// ---- 64x64 GEMM tile (R0/R6-verified): 4 waves, BK=64, dbuf, gload_lds.
// mode 0: fp32 C[.,N] + bias0. mode 1: bn<256 -> fp32 disp (ldc=256,
// bias0=b_disp); bn>=256 -> bf16 valT transpose (bias1=b_val).
__device__ __forceinline__ void gemm64_tile(
    unsigned char* smem, const unsigned short* __restrict__ A,
    const unsigned short* __restrict__ Bw, const float* __restrict__ bias0,
    const float* __restrict__ bias1, float* __restrict__ C,
    unsigned short* __restrict__ CbT, int N, int bm, int bn, int mode, int tid) {
    unsigned short* lA = (unsigned short*)smem;            // [2][8*512] = 16 KB
    unsigned short* lB = (unsigned short*)(smem + 16384);  // [2][8*512] = 16 KB
    const int K = 1024, nk = 16;
    int w = tid >> 6, lane = tid & 63;
    int wr = w & 1, wc = w >> 1;
    int m16 = lane & 15, q = lane >> 4;

    __syncthreads();   // smem reuse guard (previous stage)

    const unsigned short* aPtr[2];
    const unsigned short* bPtr[2];
#pragma unroll
    for (int i = 0; i < 2; ++i) {
        int g = w + 4 * i;
        aPtr[i] = A + (long)(bm + (g & 3) * 16 + m16) * K + (g >> 2) * 32 + q * 8;
        bPtr[i] = Bw + (long)(bn + (g & 3) * 16 + m16) * K + (g >> 2) * 32 + q * 8;
    }

    f32x4 acc[2][2];
#pragma unroll
    for (int i = 0; i < 2; ++i)
#pragma unroll
        for (int j = 0; j < 2; ++j) acc[i][j] = (f32x4){0.f, 0.f, 0.f, 0.f};

#pragma unroll
    for (int i = 0; i < 2; ++i) {
        gload_lds16(aPtr[i], &lA[(w + 4 * i) * 512]);
        gload_lds16(bPtr[i], &lB[(w + 4 * i) * 512]);
    }

    for (int kt = 0; kt < nk; ++kt) {
        int p = kt & 1;
        __syncthreads();
        if (kt + 1 < nk) {
            int ko = (kt + 1) * 64;
#pragma unroll
            for (int i = 0; i < 2; ++i) {
                gload_lds16(aPtr[i] + ko, &lA[(p ^ 1) * 4096 + (w + 4 * i) * 512]);
                gload_lds16(bPtr[i] + ko, &lB[(p ^ 1) * 4096 + (w + 4 * i) * 512]);
            }
        }
#pragma unroll
        for (int s = 0; s < 2; ++s) {
            bf16x8 af[2], bg[2];
#pragma unroll
            for (int r = 0; r < 2; ++r) {
                af[r] = *(const bf16x8*)&lA[p * 4096 + (s * 4 + wr * 2 + r) * 512 + lane * 8];
                bg[r] = *(const bf16x8*)&lB[p * 4096 + (s * 4 + wc * 2 + r) * 512 + lane * 8];
            }
#pragma unroll
            for (int r = 0; r < 2; ++r)
#pragma unroll
                for (int n = 0; n < 2; ++n)
                    acc[r][n] = __builtin_amdgcn_mfma_f32_16x16x32_bf16(af[r], bg[n], acc[r][n], 0, 0, 0);
        }
    }

    if (mode == 0 || bn < 256) {
        int ldc = (mode == 0) ? N : 256;
#pragma unroll
        for (int n = 0; n < 2; ++n) {
            int col = bn + wc * 32 + n * 16 + m16;
            float bvv = bias0[col];
#pragma unroll
            for (int r = 0; r < 2; ++r)
#pragma unroll
                for (int e = 0; e < 4; ++e) {
                    int row = bm + wr * 32 + r * 16 + q * 4 + e;
                    C[(long)row * ldc + col] = acc[r][n][e] + bvv;
                }
        }
    } else {
        // valT path: bounce through LDS; 8-lane groups store 128B contiguous
        // along t.
        __syncthreads();
        unsigned short* sC = lA;   // 64 x 64 bf16
#pragma unroll
        for (int n = 0; n < 2; ++n) {
            int col_l = wc * 32 + n * 16 + m16;
            float bvv = bias1[bn + col_l - 256];
#pragma unroll
            for (int r = 0; r < 2; ++r)
#pragma unroll
                for (int e = 0; e < 4; ++e) {
                    int row_l = wr * 32 + r * 16 + q * 4 + e;
                    sC[row_l * 64 + col_l] = f2bf(acc[r][n][e] + bvv);
                }
        }
        __syncthreads();
        long base0 = ((long)(bm >> 10)) * 1048576 + (long)(bn - 256) * 1024 + (bm & 1023);
#pragma unroll
        for (int it = 0; it < 2; ++it) {
            int slot = it * 256 + tid;     // 512 slots = 64 hs x 8 t-chunks
            int hs = slot >> 3;
            int tc = (slot & 7) * 8;
            us8 o;
#pragma unroll
            for (int j = 0; j < 8; ++j) o[j] = sC[(tc + j) * 64 + hs];
            *(us8*)&CbT[base0 + (long)hs * 1024 + tc] = o;
        }
    }
}

// packed 2-wide gelu, Pade(1,1) tanh (|u|<~0.5 -> err ~1e-3, << threshold)
__device__ __forceinline__ f32x2 gelu2(f32x2 z) {
    f32x2 z2 = z * z;
    f32x2 u = z * (0.7978845608f + 0.0356774081f * z2);
    f32x2 u2 = u * u;
    f32x2 den = 1.f + 0.33333333f * u2;
    f32x2 r;
    r.x = __builtin_amdgcn_rcpf(den.x);
    r.y = __builtin_amdgcn_rcpf(den.y);
    f32x2 th = u * r;
    f32x2 zh = 0.5f * z;
    return zh + zh * th;
}

#define PROJ_LD 36
#define SW_LD 104

// one attn tile = (b, h, 32-t rows); 256 threads / 4 waves. [R4/R6-verified]
__device__ __forceinline__ void attn_tile(
    unsigned char* smem, const float* __restrict__ disp,
    const unsigned short* __restrict__ valT, const float* __restrict__ rel,
    const float* __restrict__ Wpos, const float* __restrict__ Wf,
    const float* __restrict__ bfu, const float* __restrict__ Wb,
    const float* __restrict__ bb_p, const float* __restrict__ Wd,
    const float* __restrict__ bd_p, unsigned short* __restrict__ y,
    int tile, int tid) {
    const int T = 1024;
    unsigned short* sWd = (unsigned short*)smem;       // [32][104] = 6656 B
    float* ov = (float*)(smem + 6656);                 // 22016 B
    float* sProj = ov;                                 // [96][36]
    float* sDisp = ov + 96 * PROJ_LD;                  // [96][16]
    float* sWfT  = sDisp + 96 * 16;                    // [16][32]
    unsigned short* sValT = (unsigned short*)ov;       // phase C/D overlay [64][104]

    int t0 = (tile & 31) * 32;
    int bh = tile >> 5;
    int b = bh >> 4, h = bh & 15;
    int wave = tid >> 6, lane = tid & 63;
    int m16 = lane & 15, q = lane >> 4;

    __syncthreads();   // smem reuse guard

    // ---- Phase A: zero sWd, stage WfT + disp[96 rows], compute proj ----
    {
        uint4 z4 = make_uint4(0, 0, 0, 0);
        for (int i = tid; i < 416; i += 256) ((uint4*)sWd)[i] = z4;
        sWfT[(tid & 15) * 32 + (tid >> 4)] = Wf[tid];
        { int j = tid + 256; sWfT[(j & 15) * 32 + (j >> 4)] = Wf[j]; }
        for (int i = tid; i < 384; i += 256) {    // 96 rows x 4 quads
            int r = i >> 2, qq = i & 3;
            int ts = t0 + r - 64;
            float4 v = make_float4(0.f, 0.f, 0.f, 0.f);
            if (ts >= 0)
                v = ((const float4*)(disp + ((long)(b * T + ts) * NHEAD + h) * BDIM))[qq];
            *(float4*)&sDisp[r * 16 + qq * 4] = v;
        }
    }
    __syncthreads();
    for (int idx = tid; idx < 96 * 32; idx += 256) {
        int r = idx >> 5, k = idx & 31;
        float a = 0.f;
#pragma unroll
        for (int d = 0; d < 16; ++d) a += sDisp[r * 16 + d] * sWfT[d * 32 + k];
        sProj[r * PROJ_LD + k] = a;
    }

    // lane-constant params (lane == j)
    float relv[16];
#pragma unroll
    for (int e = 0; e < 4; ++e) {
        float4 rr = ((const float4*)rel)[lane * 4 + e];
        relv[e * 4 + 0] = rr.x; relv[e * 4 + 1] = rr.y;
        relv[e * 4 + 2] = rr.z; relv[e * 4 + 3] = rr.w;
    }
    f32x2 pfd[16], wbd[16];
#pragma unroll
    for (int d = 0; d < 16; ++d) {
        float a = 0.f;
#pragma unroll
        for (int e = 0; e < 16; ++e) a += relv[e] * Wpos[d * 16 + e];
        pfd[d].x = a + bfu[d];
        pfd[d].y = bfu[16 + d];
        wbd[d].x = Wb[d];
        wbd[d].y = Wd[d];
    }
    float bbond = *bb_p, bdmg = *bd_p;
    __syncthreads();

    // ---- Phase B: logits + softmax; 4 waves x 8 rows, lane = j ----
    // No max-shift (|logit| <~ 1); masked lanes e=0, lane 63 always valid.
    int wbase = wave * 8;
    for (int rr = 0; rr < 8; ++rr) {
        int tl = wbase + rr;
        int rs = tl + 1 + lane;       // window row in sProj (1..95)
        int rc = tl + 64;             // center row (64..95)
        bool valid = (t0 + tl + lane - 63) >= 0;
        float cb[16], cd[16], pb[16], pd[16];
        const float* crow = &sProj[rc * PROJ_LD];
        const float* prow = &sProj[rs * PROJ_LD];
#pragma unroll
        for (int qq = 0; qq < 4; ++qq) {
            float4 v1 = *(const float4*)&crow[qq * 4];
            float4 v2 = *(const float4*)&crow[16 + qq * 4];
            float4 v3 = *(const float4*)&prow[qq * 4];
            float4 v4 = *(const float4*)&prow[16 + qq * 4];
            cb[qq*4+0]=v1.x; cb[qq*4+1]=v1.y; cb[qq*4+2]=v1.z; cb[qq*4+3]=v1.w;
            cd[qq*4+0]=v2.x; cd[qq*4+1]=v2.y; cd[qq*4+2]=v2.z; cd[qq*4+3]=v2.w;
            pb[qq*4+0]=v3.x; pb[qq*4+1]=v3.y; pb[qq*4+2]=v3.z; pb[qq*4+3]=v3.w;
            pd[qq*4+0]=v4.x; pd[qq*4+1]=v4.y; pd[qq*4+2]=v4.z; pd[qq*4+3]=v4.w;
        }
        f32x2 acc2 = (f32x2){bbond, bdmg};
#pragma unroll
        for (int k = 0; k < 16; ++k) {
            f32x2 pz, cz;
            pz.x = pb[k]; pz.y = pd[k];
            cz.x = cb[k]; cz.y = cd[k];
            f32x2 z = pz - cz + pfd[k];
            acc2 = acc2 + gelu2(z) * wbd[k];
        }
        float bl = acc2.x, dm = acc2.y;
        float damage = __builtin_amdgcn_rcpf(1.f + __builtin_exp2f(-dm * LOG2E));
        float logit = bl - 10.f * damage;
        float e = valid ? __builtin_exp2f(logit * LOG2E) : 0.f;
        float ssum = e;
#pragma unroll
        for (int off = 32; off >= 1; off >>= 1) ssum += __shfl_xor(ssum, off);
        sWd[tl * SW_LD + rs] = f2bf(e * __builtin_amdgcn_rcpf(ssum));
    }
    __syncthreads();

    // ---- Phase C: stage sValT[hs][r'] (overlays ov); 64 hs x 12 granules ----
    for (int i = tid; i < 768; i += 256) {
        int g = i >> 6, hs = i & 63;    // wave-aligned: 64 consecutive i = one g
        int ts0 = t0 - 64 + g * 8;      // 8-aligned: all-or-nothing validity
        us8 v = (us8)0;
        if (ts0 >= 0)
            v = *(const us8*)&valT[((long)(b * NHEAD * HSZ + h * HSZ + hs)) * T + ts0];
        *(us8*)&sValT[hs * SW_LD + g * 8] = v;
    }
    __syncthreads();

    // ---- Phase D: out[t][hs] = sum_r sWd[t][r] * sValT[hs][r] via MFMA ----
    {
        int mi = wave & 1;              // t-tile (2 x 16 rows)
        int nh = (wave >> 1) * 2;       // hs-tile pair (4 x 16 cols)
        f32x4 acc[2];
#pragma unroll
        for (int n = 0; n < 2; ++n) acc[n] = (f32x4){0.f, 0.f, 0.f, 0.f};
#pragma unroll
        for (int kt = 0; kt < 3; ++kt) {   // k = 0..95 covers window 1..95
            bf16x8 a = *(const bf16x8*)&sWd[(mi * 16 + m16) * SW_LD + kt * 32 + q * 8];
#pragma unroll
            for (int n = 0; n < 2; ++n) {
                bf16x8 bv = *(const bf16x8*)&sValT[((nh + n) * 16 + m16) * SW_LD + kt * 32 + q * 8];
                acc[n] = __builtin_amdgcn_mfma_f32_16x16x32_bf16(a, bv, acc[n], 0, 0, 0);
            }
        }
        int trow = t0 + mi * 16 + q * 4;
#pragma unroll
        for (int n = 0; n < 2; ++n) {
            int col = h * HSZ + (nh + n) * 16 + m16;
#pragma unroll
            for (int e = 0; e < 4; ++e)
                y[(long)(b * T + trow + e) * (NHEAD * HSZ) + col] = f2bf(acc[n][e]);
        }
    }
}

// ---- persistent fused pipeline: grid 1024 = 4 blocks/CU, 256 thr ----
// LDS 32KB x4 = 128KB/CU (<160), VGPR ~84 (<128 cap at 4 waves/SIMD) ->
// all 1024 co-resident. Stage 2 is exactly 1 attn tile per block (fixes
// R6's imbalance); barriers are the two-level gsync2.
__global__ __launch_bounds__(256, 4) void fused_pipe(
    const float* __restrict__ x, const float* __restrict__ Wd_w,
    const float* __restrict__ bdp, const float* __restrict__ Wv_w,
    const float* __restrict__ bvp, const float* __restrict__ rel,
    const float* __restrict__ Wf, const float* __restrict__ bfu,
    const float* __restrict__ Wpos, const float* __restrict__ Wb,
    const float* __restrict__ bb_p, const float* __restrict__ Wdm,
    const float* __restrict__ bd_p, const float* __restrict__ Wc_w,
    const float* __restrict__ bc, float* __restrict__ out,
    float* __restrict__ disp, unsigned short* __restrict__ x_bf,
    unsigned short* __restrict__ valT, unsigned short* __restrict__ Wcat,
    unsigned short* __restrict__ Wv_bf, unsigned short* __restrict__ Wc_bf,
    unsigned short* __restrict__ y_bf, unsigned* bar) {
    __shared__ __align__(16) unsigned char smem[32768];
    int tid = threadIdx.x;
    int bid = blockIdx.x;
    int grp = bid & 7;

    // ---- stage 0: fp32->bf16 casts (grid-stride over 1,114,112 float4) ----
    {
        int gid = bid * 256 + tid;
        for (int i = gid; i < 1114112; i += 262144) {
            const float* src; unsigned short* dst; int j;
            if (i < 524288)      { src = x;    dst = x_bf;  j = i; }
            else if (i < 589824) { src = Wd_w; dst = Wcat;  j = i - 524288; }
            else if (i < 851968) { src = Wv_w; dst = Wv_bf; j = i - 589824; }
            else                 { src = Wc_w; dst = Wc_bf; j = i - 851968; }
            float4 f = ((const float4*)src)[j];
            ushort4 o;
            o.x = f2bf(f.x); o.y = f2bf(f.y); o.z = f2bf(f.z); o.w = f2bf(f.w);
            ((ushort4*)dst)[j] = o;
        }
    }
    gsync2(bar, grp);

    // ---- stage 1: gemm1 (disp | valT), 640 tiles of 64x64, N=1280 ----
    if (bid < 640) {
        int xcd = bid & 7, rr = bid >> 3;
        int bm = (xcd * 4 + (rr & 3)) * 64;
        int bn = (rr >> 2) * 64;
        gemm64_tile(smem, x_bf, Wcat, bdp, bvp, disp, valT, 1280, bm, bn, 1, tid);
    }
    gsync2(bar + 1024, grp);

    // ---- stage 2: attn, 1024 tiles, exactly 1 per block ----
    attn_tile(smem, disp, valT, rel, Wpos, Wf, bfu, Wb, bb_p, Wdm, bd_p,
              y_bf, bid, tid);
    gsync2(bar + 2048, grp);

    // ---- stage 3: gemm2 (out = y @ Wc^T + bc), 512 tiles of 64x64 ----
    if (bid < 512) {
        int xcd = bid & 7, rr = bid >> 3;
        int bm = (xcd * 4 + (rr & 3)) * 64;
        int bn = (rr >> 2) * 64;
        gemm64_tile(smem, y_bf, Wc_bf, bc, nullptr, out, nullptr, 1024, bm, bn, 0, tid);
    }
}

extern "C" void kernel_launch(void* const* d_in, const int* in_sizes, int n_in,
                              void* d_out, int out_size, void* d_ws, size_t ws_size,
                              hipStream_t stream) {
    const float* x       = (const float*)d_in[0];
    const float* W_disp  = (const float*)d_in[1];
    const float* b_disp  = (const float*)d_in[2];
    const float* W_val   = (const float*)d_in[3];
    const float* b_val   = (const float*)d_in[4];
    const float* rel     = (const float*)d_in[5];
    const float* W_fused = (const float*)d_in[6];
    const float* b_fused = (const float*)d_in[7];
    const float* W_pos   = (const float*)d_in[8];
    const float* W_bond  = (const float*)d_in[9];
    const float* b_bond  = (const float*)d_in[10];
    const float* W_dmg   = (const float*)d_in[11];
    const float* b_dmg   = (const float*)d_in[12];
    const float* W_cproj = (const float*)d_in[13];
    const float* b_cproj = (const float*)d_in[14];
    float* out = (float*)d_out;
    float* ws  = (float*)d_ws;

    // workspace layout (~14.5 MB); barrier region at +32 MB (3 sets x 4 KB).
    float* disp = ws;                                          // 524288 f
    unsigned short* x_bf  = (unsigned short*)(disp + 524288);  // 2097152 us (= y_bf)
    unsigned short* valT  = x_bf + 2097152;                    // 2097152 us
    unsigned short* Wcat  = valT + 2097152;                    // 262144 us
    unsigned short* Wv_bf = Wcat + 262144;                     // 1048576 us (adj. to Wcat)
    unsigned short* Wc_bf = Wv_bf + 1048576;                   // 1048576 us
    unsigned short* y_bf  = x_bf;
    unsigned* bar = (unsigned*)((char*)d_ws + (32u << 20));

    hipMemsetAsync(bar, 0, 3 * 4096, stream);   // zero barrier sets (capturable)

    fused_pipe<<<1024, 256, 0, stream>>>(
        x, W_disp, b_disp, W_val, b_val, rel, W_fused, b_fused, W_pos,
        W_bond, b_bond, W_dmg, b_dmg, W_cproj, b_cproj, out,
        disp, x_bf, valT, Wcat, Wv_bf, Wc_bf, y_bf, bar);
}

// Round 8
// 165.992 us; speedup vs baseline: 3.4673x; 3.4673x over previous
//
#include <hip/hip_runtime.h>

#define BDIM 16
#define HSZ 64
#define NHEAD 16
#define DELTA 64
#define LOG2E 1.4426950408889634f

typedef __bf16 bf16x8 __attribute__((ext_vector_type(8)));
typedef float f32x4 __attribute__((ext_vector_type(4)));
typedef float f32x2 __attribute__((ext_vector_type(2)));
typedef unsigned short us8 __attribute__((ext_vector_type(8)));
typedef unsigned int u32;

__device__ __forceinline__ unsigned short f2bf(float f) {
    u32 u = __float_as_uint(f);
    return (unsigned short)((u + 0x7fffu + ((u >> 16) & 1u)) >> 16);
}
__device__ __forceinline__ float bf2f(unsigned short s) {
    return __uint_as_float(((u32)s) << 16);
}

__device__ __forceinline__ void gload_lds16(const void* g, void* l) {
    __builtin_amdgcn_global_load_lds(
        (const __attribute__((address_space(1))) void*)g,
        (__attribute__((address_space(3))) void*)l, 16, 0, 0);
}

// merged float->bf16 casts for x, W_disp, W_val, W_cproj + bias concat
__global__ __launch_bounds__(256) void cast4_bf16(
    const float* __restrict__ s0, unsigned short* __restrict__ d0,
    const float* __restrict__ s1, unsigned short* __restrict__ d1,
    const float* __restrict__ s2, unsigned short* __restrict__ d2,
    const float* __restrict__ s3, unsigned short* __restrict__ d3,
    const float* __restrict__ bd, const float* __restrict__ bv,
    float* __restrict__ bcat) {
    int blk = blockIdx.x;
    if (blk == 4352) {   // bias concat: 64 f4 from b_disp, 256 f4 from b_val
        for (int t = threadIdx.x; t < 320; t += 256) {
            if (t < 64) ((float4*)bcat)[t] = ((const float4*)bd)[t];
            else        ((float4*)bcat)[t] = ((const float4*)bv)[t - 64];
        }
        return;
    }
    const float* src; unsigned short* dst; int base;
    if (blk < 2048)      { src = s0; dst = d0; base = blk; }
    else if (blk < 2304) { src = s1; dst = d1; base = blk - 2048; }
    else if (blk < 3328) { src = s2; dst = d2; base = blk - 2304; }
    else                 { src = s3; dst = d3; base = blk - 3328; }
    int i = base * 256 + threadIdx.x;
    float4 f = ((const float4*)src)[i];
    ushort4 o;
    o.x = f2bf(f.x); o.y = f2bf(f.y); o.z = f2bf(f.z); o.w = f2bf(f.w);
    ((ushort4*)dst)[i] = o;
}

// C = A[M,K] @ Bw[N,K]^T + bias.
// mode 0: fp32 out C[M x N].
// mode 1: fused disp|val: cols<256 -> fp32 disp[M x 256]; cols>=256 -> bf16
//         valT[(b*1024 + col-256)*1024 + t] via LDS-bounce transpose.
// BM=BN=BK=64, 4 waves, wave tile 32x32, double-buffered LDS. XCD-aware
// 1-D grid decode: xcd = id&7 owns 4 m-tiles x all n (working set fits L2).
__global__ __launch_bounds__(256) void gemm_bf16(const unsigned short* __restrict__ A,
                                                 const unsigned short* __restrict__ Bw,
                                                 const float* __restrict__ bias,
                                                 float* __restrict__ C,
                                                 unsigned short* __restrict__ CbT,
                                                 int N, int K, int nbx, int mode) {
    __shared__ __align__(16) unsigned short lA[2][8 * 512];
    __shared__ __align__(16) unsigned short lB[2][8 * 512];
    int tid = threadIdx.x;
    int w = tid >> 6, lane = tid & 63;
    int id = blockIdx.x;
    int xcd = id & 7, rr = id >> 3;
    int mi = xcd * 4 + (rr & 3);      // M/64 = 32 tiles, 4 per XCD
    int ni = rr >> 2;                 // 0..nbx-1
    int bm = mi * 64, bn = ni * 64;
    int wr = w & 1, wc = w >> 1;
    int m16 = lane & 15, q = lane >> 4;

    const unsigned short* aPtr[2];
    const unsigned short* bPtr[2];
#pragma unroll
    for (int i = 0; i < 2; ++i) {
        int g = w + 4 * i;
        aPtr[i] = A + (long)(bm + (g & 3) * 16 + m16) * K + (g >> 2) * 32 + q * 8;
        bPtr[i] = Bw + (long)(bn + (g & 3) * 16 + m16) * K + (g >> 2) * 32 + q * 8;
    }

    f32x4 acc[2][2];
#pragma unroll
    for (int i = 0; i < 2; ++i)
#pragma unroll
        for (int j = 0; j < 2; ++j) acc[i][j] = (f32x4){0.f, 0.f, 0.f, 0.f};

    int nk = K >> 6;
#pragma unroll
    for (int i = 0; i < 2; ++i) {
        gload_lds16(aPtr[i], &lA[0][(w + 4 * i) * 512]);
        gload_lds16(bPtr[i], &lB[0][(w + 4 * i) * 512]);
    }

    for (int kt = 0; kt < nk; ++kt) {
        int p = kt & 1;
        __syncthreads();
        if (kt + 1 < nk) {
            int ko = (kt + 1) * 64;
#pragma unroll
            for (int i = 0; i < 2; ++i) {
                gload_lds16(aPtr[i] + ko, &lA[p ^ 1][(w + 4 * i) * 512]);
                gload_lds16(bPtr[i] + ko, &lB[p ^ 1][(w + 4 * i) * 512]);
            }
        }
#pragma unroll
        for (int s = 0; s < 2; ++s) {
            bf16x8 af[2], bg[2];
#pragma unroll
            for (int r = 0; r < 2; ++r) {
                af[r] = *(const bf16x8*)&lA[p][(s * 4 + wr * 2 + r) * 512 + lane * 8];
                bg[r] = *(const bf16x8*)&lB[p][(s * 4 + wc * 2 + r) * 512 + lane * 8];
            }
#pragma unroll
            for (int r = 0; r < 2; ++r)
#pragma unroll
                for (int n = 0; n < 2; ++n)
                    acc[r][n] = __builtin_amdgcn_mfma_f32_16x16x32_bf16(af[r], bg[n], acc[r][n], 0, 0, 0);
        }
    }

    if (mode == 0 || bn < 256) {
        int ldc = (mode == 0) ? N : 256;
#pragma unroll
        for (int n = 0; n < 2; ++n) {
            int col = bn + wc * 32 + n * 16 + m16;
            float bv = bias[col];
#pragma unroll
            for (int r = 0; r < 2; ++r)
#pragma unroll
                for (int e = 0; e < 4; ++e) {
                    int row = bm + wr * 32 + r * 16 + q * 4 + e;
                    C[(long)row * ldc + col] = acc[r][n][e] + bv;
                }
        }
    } else {
        // valT path: bounce through LDS; write remapped so each 8-lane group
        // stores 128B contiguous along t (8 segments/wave vs 64 scattered).
        __syncthreads();
        unsigned short* sC = (unsigned short*)&lA[0][0];   // 64 x 64
#pragma unroll
        for (int n = 0; n < 2; ++n) {
            int col_l = wc * 32 + n * 16 + m16;
            float bv = bias[bn + col_l];
#pragma unroll
            for (int r = 0; r < 2; ++r)
#pragma unroll
                for (int e = 0; e < 4; ++e) {
                    int row_l = wr * 32 + r * 16 + q * 4 + e;
                    sC[row_l * 64 + col_l] = f2bf(acc[r][n][e] + bv);
                }
        }
        __syncthreads();
        long base0 = ((long)(bm >> 10)) * 1048576 + (long)(bn - 256) * 1024 + (bm & 1023);
#pragma unroll
        for (int it = 0; it < 2; ++it) {
            int slot = it * 256 + tid;     // 512 slots = 64 hs x 8 t-chunks
            int hs = slot >> 3;
            int tc = (slot & 7) * 8;
            us8 o;
#pragma unroll
            for (int j = 0; j < 8; ++j) o[j] = sC[(tc + j) * 64 + hs];
            *(us8*)&CbT[base0 + (long)hs * 1024 + tc] = o;
        }
    }
}

// packed 2-wide gelu, Pade(1,1) tanh: tanh(u) ~ u/(1+u^2/3); |u|<~0.5 here
// -> abs err < 4e-3 on tanh -> ~1e-3 on logits, << threshold.
__device__ __forceinline__ f32x2 gelu2(f32x2 z) {
    f32x2 z2 = z * z;
    f32x2 u = z * (0.7978845608f + 0.0356774081f * z2);
    f32x2 u2 = u * u;
    f32x2 den = 1.f + 0.33333333f * u2;
    f32x2 r;
    r.x = __builtin_amdgcn_rcpf(den.x);
    r.y = __builtin_amdgcn_rcpf(den.y);
    f32x2 th = u * r;
    f32x2 zh = 0.5f * z;
    return zh + zh * th;
}

#define PROJ_LD 36
#define VW_LD 136

// One block per (b, h, 64-t tile). 512 threads / 8 waves (R9/R12 config).
__global__ __launch_bounds__(512) void attn_kernel(
    const float* __restrict__ disp,             // (B,T,NH,BD) fp32
    const unsigned short* __restrict__ valT,    // (B, NH*HS, T) bf16
    const float* __restrict__ rel,              // (64,16)
    const float* __restrict__ Wpos,             // (16,16)
    const float* __restrict__ Wf,               // (32,16)
    const float* __restrict__ bfu,              // (32,)
    const float* __restrict__ Wb,               // (16,)
    const float* __restrict__ bb_p,             // scalar
    const float* __restrict__ Wd,               // (16,)
    const float* __restrict__ bd_p,             // scalar
    unsigned short* __restrict__ y,             // (B,T,C) bf16
    int T) {
    __shared__ __align__(16) unsigned short sWd[64 * VW_LD];  // 17408 B dense weights
    __shared__ __align__(16) float ov[128 * PROJ_LD + 128 * 16 + 512];  // 28672 B
    float* sProj = ov;                      // [128][36]
    float* sDisp = ov + 128 * PROJ_LD;      // [128][16]
    float* sWfT  = sDisp + 128 * 16;        // [16][32] transposed
    unsigned short* sValT = (unsigned short*)ov;   // phase D overlay [64][136]

    int tid = threadIdx.x;
    int ntile = T / 64;
    int t0 = (blockIdx.x % ntile) * 64;
    int bh = blockIdx.x / ntile;
    int b = bh / NHEAD, h = bh % NHEAD;
    int wave = tid >> 6, lane = tid & 63;
    int m16 = lane & 15, q = lane >> 4;

    // ---- Phase A: zero sWd (full 1088 uint4), stage WfT + disp, compute proj ----
    {
        uint4 z4 = make_uint4(0, 0, 0, 0);
        for (int i = tid; i < 1088; i += 512) ((uint4*)sWd)[i] = z4;
        sWfT[(tid & 15) * 32 + (tid >> 4)] = Wf[tid];   // 512 entries
        {
            int r = tid >> 2, qq = tid & 3;     // 128 rows x 4 quads
            int ts = t0 + r - 64;
            float4 v = make_float4(0.f, 0.f, 0.f, 0.f);
            if (ts >= 0)
                v = ((const float4*)(disp + ((long)(b * T + ts) * NHEAD + h) * BDIM))[qq];
            *(float4*)&sDisp[r * 16 + qq * 4] = v;
        }
    }
    __syncthreads();
    for (int idx = tid; idx < 128 * 32; idx += 512) {
        int r = idx >> 5, k = idx & 31;
        float a = 0.f;
#pragma unroll
        for (int d = 0; d < 16; ++d) a += sDisp[r * 16 + d] * sWfT[d * 32 + k];
        sProj[r * PROJ_LD + k] = a;
    }

    // lane-constant params (lane == j): pos_feat in-register; packed pairs
    float relv[16];
#pragma unroll
    for (int e = 0; e < 4; ++e) {
        float4 rr = ((const float4*)rel)[lane * 4 + e];
        relv[e * 4 + 0] = rr.x; relv[e * 4 + 1] = rr.y;
        relv[e * 4 + 2] = rr.z; relv[e * 4 + 3] = rr.w;
    }
    f32x2 pfd[16], wbd[16];
#pragma unroll
    for (int d = 0; d < 16; ++d) {
        float a = 0.f;
#pragma unroll
        for (int e = 0; e < 16; ++e) a += relv[e] * Wpos[d * 16 + e];
        pfd[d].x = a + bfu[d];
        pfd[d].y = bfu[16 + d];
        wbd[d].x = Wb[d];
        wbd[d].y = Wd[d];
    }
    float bbond = *bb_p, bdmg = *bd_p;
    __syncthreads();

    // ---- Phase B: logits + softmax; wave per t-row (8 rows/wave), lane = j ----
    // NOTE: no max-reduction. Weights are 0.02-scale => |logit| <~ 1, so
    // exp2 cannot overflow; softmax is shift-invariant. Masked lanes: e = 0
    // (lane j=63 is always valid -> sum > 0). Halves the serial shuffle chain.
    int wbase = wave * 8;
    for (int rr = 0; rr < 8; ++rr) {
        int tl = wbase + rr;
        int rs = tl + 1 + lane;       // source window row
        int rc = tl + 64;             // center row
        bool valid = (t0 + tl + lane - 63) >= 0;
        float cb[16], cd[16], pb[16], pd[16];
        const float* crow = &sProj[rc * PROJ_LD];
        const float* prow = &sProj[rs * PROJ_LD];
#pragma unroll
        for (int qq = 0; qq < 4; ++qq) {
            float4 v1 = *(const float4*)&crow[qq * 4];
            float4 v2 = *(const float4*)&crow[16 + qq * 4];
            float4 v3 = *(const float4*)&prow[qq * 4];
            float4 v4 = *(const float4*)&prow[16 + qq * 4];
            cb[qq*4+0]=v1.x; cb[qq*4+1]=v1.y; cb[qq*4+2]=v1.z; cb[qq*4+3]=v1.w;
            cd[qq*4+0]=v2.x; cd[qq*4+1]=v2.y; cd[qq*4+2]=v2.z; cd[qq*4+3]=v2.w;
            pb[qq*4+0]=v3.x; pb[qq*4+1]=v3.y; pb[qq*4+2]=v3.z; pb[qq*4+3]=v3.w;
            pd[qq*4+0]=v4.x; pd[qq*4+1]=v4.y; pd[qq*4+2]=v4.z; pd[qq*4+3]=v4.w;
        }
        f32x2 acc2 = (f32x2){bbond, bdmg};
#pragma unroll
        for (int k = 0; k < 16; ++k) {
            f32x2 pz, cz;
            pz.x = pb[k]; pz.y = pd[k];
            cz.x = cb[k]; cz.y = cd[k];
            f32x2 z = pz - cz + pfd[k];
            acc2 = acc2 + gelu2(z) * wbd[k];
        }
        float bl = acc2.x, dm = acc2.y;
        float damage = __builtin_amdgcn_rcpf(1.f + __builtin_exp2f(-dm * LOG2E));
        float logit = bl - 10.f * damage;
        float e = valid ? __builtin_exp2f(logit * LOG2E) : 0.f;
        float ssum = e;
#pragma unroll
        for (int off = 32; off >= 1; off >>= 1) ssum += __shfl_xor(ssum, off);
        sWd[tl * VW_LD + rs] = f2bf(e * __builtin_amdgcn_rcpf(ssum));
    }
    __syncthreads();

    // ---- stage sValT[hs][r'] from valT (coalesced along t; overlays ov) ----
    {
        int hs = lane;                      // 0..63
        long vbase = ((long)(b * NHEAD * HSZ + h * HSZ + hs)) * T + (t0 - 64);
#pragma unroll
        for (int it = 0; it < 2; ++it) {
            int g = wave * 2 + it;          // granule 0..15, r' = g*8..g*8+7
            int ts0 = t0 - 64 + g * 8;
            us8 v = (us8)0;
            if (ts0 >= 0) v = *(const us8*)&valT[vbase + g * 8];
            *(us8*)&sValT[hs * VW_LD + g * 8] = v;
        }
    }
    __syncthreads();

    // ---- Phase D: out[t][hs] = sum_r sWd[t][r] * sValT[hs][r] via MFMA ----
    {
        int mi = wave >> 1;                 // t-tile
        int nh = (wave & 1) * 2;            // n-pair
        int kt0 = mi >> 1;                  // band coverage: 3 k-steps
        f32x4 acc[2];
#pragma unroll
        for (int n = 0; n < 2; ++n) acc[n] = (f32x4){0.f, 0.f, 0.f, 0.f};
#pragma unroll
        for (int kk = 0; kk < 3; ++kk) {
            int kt = kt0 + kk;
            bf16x8 a = *(const bf16x8*)&sWd[(mi * 16 + m16) * VW_LD + kt * 32 + q * 8];
#pragma unroll
            for (int n = 0; n < 2; ++n) {
                bf16x8 bv = *(const bf16x8*)&sValT[((nh + n) * 16 + m16) * VW_LD + kt * 32 + q * 8];
                acc[n] = __builtin_amdgcn_mfma_f32_16x16x32_bf16(a, bv, acc[n], 0, 0, 0);
            }
        }
        int trow = t0 + mi * 16 + q * 4;
#pragma unroll
        for (int n = 0; n < 2; ++n) {
            int col = h * HSZ + (nh + n) * 16 + m16;
#pragma unroll
            for (int e = 0; e < 4; ++e)
                y[(long)(b * T + trow + e) * (NHEAD * HSZ) + col] = f2bf(acc[n][e]);
        }
    }
}

extern "C" void kernel_launch(void* const* d_in, const int* in_sizes, int n_in,
                              void* d_out, int out_size, void* d_ws, size_t ws_size,
                              hipStream_t stream) {
    const float* x       = (const float*)d_in[0];
    const float* W_disp  = (const float*)d_in[1];
    const float* b_disp  = (const float*)d_in[2];
    const float* W_val   = (const float*)d_in[3];
    const float* b_val   = (const float*)d_in[4];
    const float* rel     = (const float*)d_in[5];
    const float* W_fused = (const float*)d_in[6];
    const float* b_fused = (const float*)d_in[7];
    const float* W_pos   = (const float*)d_in[8];
    const float* W_bond  = (const float*)d_in[9];
    const float* b_bond  = (const float*)d_in[10];
    const float* W_dmg   = (const float*)d_in[11];
    const float* b_dmg   = (const float*)d_in[12];
    const float* W_cproj = (const float*)d_in[13];
    const float* b_cproj = (const float*)d_in[14];
    float* out = (float*)d_out;
    float* ws  = (float*)d_ws;

    const int B = 2, T = 1024, C = 1024;
    // workspace layout
    float* disp = ws;                                        // 524288 f
    float* bcat = disp + 524288;                             // 1280 f
    unsigned short* x_bf  = (unsigned short*)(bcat + 1280);  // 2097152 us (reused as y_bf)
    unsigned short* valT  = x_bf + 2097152;                  // 2097152 us
    unsigned short* Wcat  = valT + 2097152;                  // 262144 + 1048576 us
    unsigned short* Wv_bf = Wcat + 262144;
    unsigned short* Wc_bf = Wv_bf + 1048576;                 // 1048576 us
    unsigned short* y_bf  = x_bf;

    cast4_bf16<<<4353, 256, 0, stream>>>(x, x_bf, W_disp, Wcat, W_val, Wv_bf,
                                         W_cproj, Wc_bf, b_disp, b_val, bcat);

    // fused disp|val GEMM: N = 1280, grid 32 m-tiles x 20 n-tiles = 640
    gemm_bf16<<<640, 256, 0, stream>>>(x_bf, Wcat, bcat, disp, valT,
                                       1280, C, 20, 1);
    attn_kernel<<<dim3(B * NHEAD * (T / 64)), 512, 0, stream>>>(
        disp, valT, rel, W_pos, W_fused, b_fused, W_bond, b_bond, W_dmg, b_dmg,
        y_bf, T);
    // out = y @ W_cproj^T + b_cproj (fp32), grid 32 x 16 = 512
    gemm_bf16<<<512, 256, 0, stream>>>(y_bf, Wc_bf, b_cproj, out, nullptr,
                                       C, C, 16, 0);
}

// Round 9
// 165.648 us; speedup vs baseline: 3.4745x; 1.0021x over previous
//
#include <hip/hip_runtime.h>

#define BDIM 16
#define HSZ 64
#define NHEAD 16
#define DELTA 64
#define LOG2E 1.4426950408889634f

typedef __bf16 bf16x8 __attribute__((ext_vector_type(8)));
typedef float f32x4 __attribute__((ext_vector_type(4)));
typedef float f32x2 __attribute__((ext_vector_type(2)));
typedef unsigned short us8 __attribute__((ext_vector_type(8)));
typedef unsigned int u32;

__device__ __forceinline__ unsigned short f2bf(float f) {
    u32 u = __float_as_uint(f);
    return (unsigned short)((u + 0x7fffu + ((u >> 16) & 1u)) >> 16);
}
__device__ __forceinline__ float bf2f(unsigned short s) {
    return __uint_as_float(((u32)s) << 16);
}

__device__ __forceinline__ void gload_lds16(const void* g, void* l) {
    __builtin_amdgcn_global_load_lds(
        (const __attribute__((address_space(1))) void*)g,
        (__attribute__((address_space(3))) void*)l, 16, 0, 0);
}

// merged float->bf16 casts for x, W_disp, W_val, W_cproj + bias concat
__global__ __launch_bounds__(256) void cast4_bf16(
    const float* __restrict__ s0, unsigned short* __restrict__ d0,
    const float* __restrict__ s1, unsigned short* __restrict__ d1,
    const float* __restrict__ s2, unsigned short* __restrict__ d2,
    const float* __restrict__ s3, unsigned short* __restrict__ d3,
    const float* __restrict__ bd, const float* __restrict__ bv,
    float* __restrict__ bcat) {
    int blk = blockIdx.x;
    if (blk == 4352) {   // bias concat: 64 f4 from b_disp, 256 f4 from b_val
        for (int t = threadIdx.x; t < 320; t += 256) {
            if (t < 64) ((float4*)bcat)[t] = ((const float4*)bd)[t];
            else        ((float4*)bcat)[t] = ((const float4*)bv)[t - 64];
        }
        return;
    }
    const float* src; unsigned short* dst; int base;
    if (blk < 2048)      { src = s0; dst = d0; base = blk; }
    else if (blk < 2304) { src = s1; dst = d1; base = blk - 2048; }
    else if (blk < 3328) { src = s2; dst = d2; base = blk - 2304; }
    else                 { src = s3; dst = d3; base = blk - 3328; }
    int i = base * 256 + threadIdx.x;
    float4 f = ((const float4*)src)[i];
    ushort4 o;
    o.x = f2bf(f.x); o.y = f2bf(f.y); o.z = f2bf(f.z); o.w = f2bf(f.w);
    ((ushort4*)dst)[i] = o;
}

// C = A[M,K] @ Bw[N,K]^T + bias.
// mode 0: fp32 out C[M x N].
// mode 1: fused disp|val: cols<256 -> fp32 disp[M x 256]; cols>=256 -> bf16
//         valT[(b*1024 + col-256)*1024 + t] via LDS-bounce transpose.
// BM=BN=BK=64, 4 waves, wave tile 32x32. R9 change: 3-deep LDS pipeline with
// COUNTED vmcnt + raw s_barrier (T4) -- __syncthreads() drains vmcnt(0) and
// exposes ~650 cyc of HBM latency per K-step (the only axis never tested;
// R1/R4 kept full-drain barriers). vmcnt(8) keeps 2 steps (8 loads/wave)
// in flight across barriers. LDS 48 KB -> still 3 blocks/CU.
__global__ __launch_bounds__(256) void gemm_bf16(const unsigned short* __restrict__ A,
                                                 const unsigned short* __restrict__ Bw,
                                                 const float* __restrict__ bias,
                                                 float* __restrict__ C,
                                                 unsigned short* __restrict__ CbT,
                                                 int N, int K, int nbx, int mode) {
    __shared__ __align__(16) unsigned short lA[3][8 * 512];   // 24 KB
    __shared__ __align__(16) unsigned short lB[3][8 * 512];   // 24 KB
    int tid = threadIdx.x;
    int w = tid >> 6, lane = tid & 63;
    int id = blockIdx.x;
    int xcd = id & 7, rr = id >> 3;
    int mi = xcd * 4 + (rr & 3);      // M/64 = 32 tiles, 4 per XCD
    int ni = rr >> 2;                 // 0..nbx-1
    int bm = mi * 64, bn = ni * 64;
    int wr = w & 1, wc = w >> 1;
    int m16 = lane & 15, q = lane >> 4;

    const unsigned short* aPtr[2];
    const unsigned short* bPtr[2];
#pragma unroll
    for (int i = 0; i < 2; ++i) {
        int g = w + 4 * i;
        aPtr[i] = A + (long)(bm + (g & 3) * 16 + m16) * K + (g >> 2) * 32 + q * 8;
        bPtr[i] = Bw + (long)(bn + (g & 3) * 16 + m16) * K + (g >> 2) * 32 + q * 8;
    }

    f32x4 acc[2][2];
#pragma unroll
    for (int i = 0; i < 2; ++i)
#pragma unroll
        for (int j = 0; j < 2; ++j) acc[i][j] = (f32x4){0.f, 0.f, 0.f, 0.f};

    int nk = K >> 6;   // 16

#define ISSUE_STEP(KT, BUF)                                                 \
    {                                                                       \
        int ko = (KT) * 64;                                                 \
        _Pragma("unroll")                                                   \
        for (int i = 0; i < 2; ++i) {                                       \
            gload_lds16(aPtr[i] + ko, &lA[BUF][(w + 4 * i) * 512]);         \
            gload_lds16(bPtr[i] + ko, &lB[BUF][(w + 4 * i) * 512]);         \
        }                                                                   \
    }
#define MFMA_STEP(CUR)                                                      \
    {                                                                       \
        _Pragma("unroll")                                                   \
        for (int s = 0; s < 2; ++s) {                                       \
            bf16x8 af[2], bg[2];                                            \
            _Pragma("unroll")                                               \
            for (int r = 0; r < 2; ++r) {                                   \
                af[r] = *(const bf16x8*)&lA[CUR][(s * 4 + wr * 2 + r) * 512 + lane * 8]; \
                bg[r] = *(const bf16x8*)&lB[CUR][(s * 4 + wc * 2 + r) * 512 + lane * 8]; \
            }                                                               \
            _Pragma("unroll")                                               \
            for (int r = 0; r < 2; ++r)                                     \
                _Pragma("unroll")                                           \
                for (int n = 0; n < 2; ++n)                                 \
                    acc[r][n] = __builtin_amdgcn_mfma_f32_16x16x32_bf16(af[r], bg[n], acc[r][n], 0, 0, 0); \
        }                                                                   \
    }

    // prologue: fill 3 buffers (12 loads/wave in flight)
    ISSUE_STEP(0, 0);
    ISSUE_STEP(1, 1);
    ISSUE_STEP(2, 2);

    int cur = 0;
    for (int kt = 0; kt < nk - 2; ++kt) {
        // counted wait: oldest step's 4 loads done; 8 (2 steps) stay in flight
        asm volatile("s_waitcnt vmcnt(8)\n\ts_barrier" ::: "memory");
        __builtin_amdgcn_sched_barrier(0);
        MFMA_STEP(cur);
        __builtin_amdgcn_sched_barrier(0);
        // all waves done reading buf[cur] before its overwrite is issued
        asm volatile("s_barrier" ::: "memory");
        if (kt + 3 < nk) ISSUE_STEP(kt + 3, cur);
        cur = (cur == 2) ? 0 : cur + 1;
    }
    // tail: step nk-2 (8 outstanding -> wait to 4), step nk-1 (wait to 0)
    asm volatile("s_waitcnt vmcnt(4)\n\ts_barrier" ::: "memory");
    __builtin_amdgcn_sched_barrier(0);
    MFMA_STEP(cur);
    cur = (cur == 2) ? 0 : cur + 1;
    asm volatile("s_waitcnt vmcnt(0)\n\ts_barrier" ::: "memory");
    __builtin_amdgcn_sched_barrier(0);
    MFMA_STEP(cur);
#undef ISSUE_STEP
#undef MFMA_STEP

    if (mode == 0 || bn < 256) {
        int ldc = (mode == 0) ? N : 256;
#pragma unroll
        for (int n = 0; n < 2; ++n) {
            int col = bn + wc * 32 + n * 16 + m16;
            float bv = bias[col];
#pragma unroll
            for (int r = 0; r < 2; ++r)
#pragma unroll
                for (int e = 0; e < 4; ++e) {
                    int row = bm + wr * 32 + r * 16 + q * 4 + e;
                    C[(long)row * ldc + col] = acc[r][n][e] + bv;
                }
        }
    } else {
        // valT path: bounce through LDS; write remapped so each 8-lane group
        // stores 128B contiguous along t (8 segments/wave vs 64 scattered).
        __syncthreads();
        unsigned short* sC = (unsigned short*)&lA[0][0];   // 64 x 64
#pragma unroll
        for (int n = 0; n < 2; ++n) {
            int col_l = wc * 32 + n * 16 + m16;
            float bv = bias[bn + col_l];
#pragma unroll
            for (int r = 0; r < 2; ++r)
#pragma unroll
                for (int e = 0; e < 4; ++e) {
                    int row_l = wr * 32 + r * 16 + q * 4 + e;
                    sC[row_l * 64 + col_l] = f2bf(acc[r][n][e] + bv);
                }
        }
        __syncthreads();
        long base0 = ((long)(bm >> 10)) * 1048576 + (long)(bn - 256) * 1024 + (bm & 1023);
#pragma unroll
        for (int it = 0; it < 2; ++it) {
            int slot = it * 256 + tid;     // 512 slots = 64 hs x 8 t-chunks
            int hs = slot >> 3;
            int tc = (slot & 7) * 8;
            us8 o;
#pragma unroll
            for (int j = 0; j < 8; ++j) o[j] = sC[(tc + j) * 64 + hs];
            *(us8*)&CbT[base0 + (long)hs * 1024 + tc] = o;
        }
    }
}

// packed 2-wide gelu, Pade(1,1) tanh: tanh(u) ~ u/(1+u^2/3); |u|<~0.5 here
// -> abs err < 4e-3 on tanh -> ~1e-3 on logits, << threshold.
__device__ __forceinline__ f32x2 gelu2(f32x2 z) {
    f32x2 z2 = z * z;
    f32x2 u = z * (0.7978845608f + 0.0356774081f * z2);
    f32x2 u2 = u * u;
    f32x2 den = 1.f + 0.33333333f * u2;
    f32x2 r;
    r.x = __builtin_amdgcn_rcpf(den.x);
    r.y = __builtin_amdgcn_rcpf(den.y);
    f32x2 th = u * r;
    f32x2 zh = 0.5f * z;
    return zh + zh * th;
}

#define PROJ_LD 36
#define VW_LD 136

// One block per (b, h, 64-t tile). 512 threads / 8 waves. [R8-verified]
__global__ __launch_bounds__(512) void attn_kernel(
    const float* __restrict__ disp,             // (B,T,NH,BD) fp32
    const unsigned short* __restrict__ valT,    // (B, NH*HS, T) bf16
    const float* __restrict__ rel,              // (64,16)
    const float* __restrict__ Wpos,             // (16,16)
    const float* __restrict__ Wf,               // (32,16)
    const float* __restrict__ bfu,              // (32,)
    const float* __restrict__ Wb,               // (16,)
    const float* __restrict__ bb_p,             // scalar
    const float* __restrict__ Wd,               // (16,)
    const float* __restrict__ bd_p,             // scalar
    unsigned short* __restrict__ y,             // (B,T,C) bf16
    int T) {
    __shared__ __align__(16) unsigned short sWd[64 * VW_LD];  // 17408 B dense weights
    __shared__ __align__(16) float ov[128 * PROJ_LD + 128 * 16 + 512];  // 28672 B
    float* sProj = ov;                      // [128][36]
    float* sDisp = ov + 128 * PROJ_LD;      // [128][16]
    float* sWfT  = sDisp + 128 * 16;        // [16][32] transposed
    unsigned short* sValT = (unsigned short*)ov;   // phase D overlay [64][136]

    int tid = threadIdx.x;
    int ntile = T / 64;
    int t0 = (blockIdx.x % ntile) * 64;
    int bh = blockIdx.x / ntile;
    int b = bh / NHEAD, h = bh % NHEAD;
    int wave = tid >> 6, lane = tid & 63;
    int m16 = lane & 15, q = lane >> 4;

    // ---- Phase A: zero sWd (full 1088 uint4), stage WfT + disp, compute proj ----
    {
        uint4 z4 = make_uint4(0, 0, 0, 0);
        for (int i = tid; i < 1088; i += 512) ((uint4*)sWd)[i] = z4;
        sWfT[(tid & 15) * 32 + (tid >> 4)] = Wf[tid];   // 512 entries
        {
            int r = tid >> 2, qq = tid & 3;     // 128 rows x 4 quads
            int ts = t0 + r - 64;
            float4 v = make_float4(0.f, 0.f, 0.f, 0.f);
            if (ts >= 0)
                v = ((const float4*)(disp + ((long)(b * T + ts) * NHEAD + h) * BDIM))[qq];
            *(float4*)&sDisp[r * 16 + qq * 4] = v;
        }
    }
    __syncthreads();
    for (int idx = tid; idx < 128 * 32; idx += 512) {
        int r = idx >> 5, k = idx & 31;
        float a = 0.f;
#pragma unroll
        for (int d = 0; d < 16; ++d) a += sDisp[r * 16 + d] * sWfT[d * 32 + k];
        sProj[r * PROJ_LD + k] = a;
    }

    // lane-constant params (lane == j): pos_feat in-register; packed pairs
    float relv[16];
#pragma unroll
    for (int e = 0; e < 4; ++e) {
        float4 rr = ((const float4*)rel)[lane * 4 + e];
        relv[e * 4 + 0] = rr.x; relv[e * 4 + 1] = rr.y;
        relv[e * 4 + 2] = rr.z; relv[e * 4 + 3] = rr.w;
    }
    f32x2 pfd[16], wbd[16];
#pragma unroll
    for (int d = 0; d < 16; ++d) {
        float a = 0.f;
#pragma unroll
        for (int e = 0; e < 16; ++e) a += relv[e] * Wpos[d * 16 + e];
        pfd[d].x = a + bfu[d];
        pfd[d].y = bfu[16 + d];
        wbd[d].x = Wb[d];
        wbd[d].y = Wd[d];
    }
    float bbond = *bb_p, bdmg = *bd_p;
    __syncthreads();

    // ---- Phase B: logits + softmax; wave per t-row (8 rows/wave), lane = j ----
    // NOTE: no max-reduction. Weights are 0.02-scale => |logit| <~ 1, so
    // exp2 cannot overflow; softmax is shift-invariant. Masked lanes: e = 0
    // (lane j=63 is always valid -> sum > 0). Halves the serial shuffle chain.
    int wbase = wave * 8;
    for (int rr = 0; rr < 8; ++rr) {
        int tl = wbase + rr;
        int rs = tl + 1 + lane;       // source window row
        int rc = tl + 64;             // center row
        bool valid = (t0 + tl + lane - 63) >= 0;
        float cb[16], cd[16], pb[16], pd[16];
        const float* crow = &sProj[rc * PROJ_LD];
        const float* prow = &sProj[rs * PROJ_LD];
#pragma unroll
        for (int qq = 0; qq < 4; ++qq) {
            float4 v1 = *(const float4*)&crow[qq * 4];
            float4 v2 = *(const float4*)&crow[16 + qq * 4];
            float4 v3 = *(const float4*)&prow[qq * 4];
            float4 v4 = *(const float4*)&prow[16 + qq * 4];
            cb[qq*4+0]=v1.x; cb[qq*4+1]=v1.y; cb[qq*4+2]=v1.z; cb[qq*4+3]=v1.w;
            cd[qq*4+0]=v2.x; cd[qq*4+1]=v2.y; cd[qq*4+2]=v2.z; cd[qq*4+3]=v2.w;
            pb[qq*4+0]=v3.x; pb[qq*4+1]=v3.y; pb[qq*4+2]=v3.z; pb[qq*4+3]=v3.w;
            pd[qq*4+0]=v4.x; pd[qq*4+1]=v4.y; pd[qq*4+2]=v4.z; pd[qq*4+3]=v4.w;
        }
        f32x2 acc2 = (f32x2){bbond, bdmg};
#pragma unroll
        for (int k = 0; k < 16; ++k) {
            f32x2 pz, cz;
            pz.x = pb[k]; pz.y = pd[k];
            cz.x = cb[k]; cz.y = cd[k];
            f32x2 z = pz - cz + pfd[k];
            acc2 = acc2 + gelu2(z) * wbd[k];
        }
        float bl = acc2.x, dm = acc2.y;
        float damage = __builtin_amdgcn_rcpf(1.f + __builtin_exp2f(-dm * LOG2E));
        float logit = bl - 10.f * damage;
        float e = valid ? __builtin_exp2f(logit * LOG2E) : 0.f;
        float ssum = e;
#pragma unroll
        for (int off = 32; off >= 1; off >>= 1) ssum += __shfl_xor(ssum, off);
        sWd[tl * VW_LD + rs] = f2bf(e * __builtin_amdgcn_rcpf(ssum));
    }
    __syncthreads();

    // ---- stage sValT[hs][r'] from valT (coalesced along t; overlays ov) ----
    {
        int hs = lane;                      // 0..63
        long vbase = ((long)(b * NHEAD * HSZ + h * HSZ + hs)) * T + (t0 - 64);
#pragma unroll
        for (int it = 0; it < 2; ++it) {
            int g = wave * 2 + it;          // granule 0..15, r' = g*8..g*8+7
            int ts0 = t0 - 64 + g * 8;
            us8 v = (us8)0;
            if (ts0 >= 0) v = *(const us8*)&valT[vbase + g * 8];
            *(us8*)&sValT[hs * VW_LD + g * 8] = v;
        }
    }
    __syncthreads();

    // ---- Phase D: out[t][hs] = sum_r sWd[t][r] * sValT[hs][r] via MFMA ----
    {
        int mi = wave >> 1;                 // t-tile
        int nh = (wave & 1) * 2;            // n-pair
        int kt0 = mi >> 1;                  // band coverage: 3 k-steps
        f32x4 acc[2];
#pragma unroll
        for (int n = 0; n < 2; ++n) acc[n] = (f32x4){0.f, 0.f, 0.f, 0.f};
#pragma unroll
        for (int kk = 0; kk < 3; ++kk) {
            int kt = kt0 + kk;
            bf16x8 a = *(const bf16x8*)&sWd[(mi * 16 + m16) * VW_LD + kt * 32 + q * 8];
#pragma unroll
            for (int n = 0; n < 2; ++n) {
                bf16x8 bv = *(const bf16x8*)&sValT[((nh + n) * 16 + m16) * VW_LD + kt * 32 + q * 8];
                acc[n] = __builtin_amdgcn_mfma_f32_16x16x32_bf16(a, bv, acc[n], 0, 0, 0);
            }
        }
        int trow = t0 + mi * 16 + q * 4;
#pragma unroll
        for (int n = 0; n < 2; ++n) {
            int col = h * HSZ + (nh + n) * 16 + m16;
#pragma unroll
            for (int e = 0; e < 4; ++e)
                y[(long)(b * T + trow + e) * (NHEAD * HSZ) + col] = f2bf(acc[n][e]);
        }
    }
}

extern "C" void kernel_launch(void* const* d_in, const int* in_sizes, int n_in,
                              void* d_out, int out_size, void* d_ws, size_t ws_size,
                              hipStream_t stream) {
    const float* x       = (const float*)d_in[0];
    const float* W_disp  = (const float*)d_in[1];
    const float* b_disp  = (const float*)d_in[2];
    const float* W_val   = (const float*)d_in[3];
    const float* b_val   = (const float*)d_in[4];
    const float* rel     = (const float*)d_in[5];
    const float* W_fused = (const float*)d_in[6];
    const float* b_fused = (const float*)d_in[7];
    const float* W_pos   = (const float*)d_in[8];
    const float* W_bond  = (const float*)d_in[9];
    const float* b_bond  = (const float*)d_in[10];
    const float* W_dmg   = (const float*)d_in[11];
    const float* b_dmg   = (const float*)d_in[12];
    const float* W_cproj = (const float*)d_in[13];
    const float* b_cproj = (const float*)d_in[14];
    float* out = (float*)d_out;
    float* ws  = (float*)d_ws;

    const int B = 2, T = 1024, C = 1024;
    // workspace layout
    float* disp = ws;                                        // 524288 f
    float* bcat = disp + 524288;                             // 1280 f
    unsigned short* x_bf  = (unsigned short*)(bcat + 1280);  // 2097152 us (reused as y_bf)
    unsigned short* valT  = x_bf + 2097152;                  // 2097152 us
    unsigned short* Wcat  = valT + 2097152;                  // 262144 + 1048576 us
    unsigned short* Wv_bf = Wcat + 262144;
    unsigned short* Wc_bf = Wv_bf + 1048576;                 // 1048576 us
    unsigned short* y_bf  = x_bf;

    cast4_bf16<<<4353, 256, 0, stream>>>(x, x_bf, W_disp, Wcat, W_val, Wv_bf,
                                         W_cproj, Wc_bf, b_disp, b_val, bcat);

    // fused disp|val GEMM: N = 1280, grid 32 m-tiles x 20 n-tiles = 640
    gemm_bf16<<<640, 256, 0, stream>>>(x_bf, Wcat, bcat, disp, valT,
                                       1280, C, 20, 1);
    attn_kernel<<<dim3(B * NHEAD * (T / 64)), 512, 0, stream>>>(
        disp, valT, rel, W_pos, W_fused, b_fused, W_bond, b_bond, W_dmg, b_dmg,
        y_bf, T);
    // out = y @ W_cproj^T + b_cproj (fp32), grid 32 x 16 = 512
    gemm_bf16<<<512, 256, 0, stream>>>(y_bf, Wc_bf, b_cproj, out, nullptr,
                                       C, C, 16, 0);
}